// Round 2
// baseline (1863.659 us; speedup 1.0000x reference)
//
#include <hip/hip_runtime.h>
#include <hip/hip_bf16.h>
#include <math.h>

// Problem constants
#define B 8
#define C 512
#define H 64
#define W 64
#define N 32768   // B*H*W tokens
#define K 1024    // clusters
#define HW 4096   // H*W
#define CHW 2097152 // C*H*W

// ws layout (float offsets)
#define MN_OFF    0                      // K*C floats: normalized codebook
#define INV_OFF   (MN_OFF + K*C)         // N floats: 1/||xf_row||
#define SMAX_OFF  (INV_OFF + N)          // N floats: row max of score
#define SDEN_OFF  (SMAX_OFF + N)         // N floats: 1/sum(exp(s-max))
#define IDX_OFF   (SDEN_OFF + N)         // N ints: argmax
#define CNT_OFF   (IDX_OFF + N)          // K floats: counts
#define ESUM_OFF  (CNT_OFF + K)          // K*C floats
#define NEWM_OFF  (ESUM_OFF + K*C)       // K*C floats
#define SCORE_OFF (NEWM_OFF + K*C)       // N*K bf16 (ushort)

static __device__ __forceinline__ unsigned short f2bf(float f) {
    unsigned int u = __float_as_uint(f);
    u += 0x7fffu + ((u >> 16) & 1u);   // RNE
    return (unsigned short)(u >> 16);
}
static __device__ __forceinline__ float bf2f(unsigned int us) {
    return __uint_as_float(us << 16);
}

// ---- normalize codebook rows: mn = m / max(||m||,1e-12) ----
__global__ void k_norm_m(const float* __restrict__ m, float* __restrict__ mn) {
    int j = blockIdx.x;
    int lane = threadIdx.x;  // 64
    const float4* mr = (const float4*)(m + (size_t)j * C);
    float4 a = mr[lane * 2], b = mr[lane * 2 + 1];
    float ss = a.x*a.x + a.y*a.y + a.z*a.z + a.w*a.w
             + b.x*b.x + b.y*b.y + b.z*b.z + b.w*b.w;
#pragma unroll
    for (int o = 32; o >= 1; o >>= 1) ss += __shfl_xor(ss, o);
    float inv = 1.0f / fmaxf(sqrtf(ss), 1e-12f);
    a.x *= inv; a.y *= inv; a.z *= inv; a.w *= inv;
    b.x *= inv; b.y *= inv; b.z *= inv; b.w *= inv;
    float4* outr = (float4*)(mn + (size_t)j * C);
    outr[lane * 2] = a; outr[lane * 2 + 1] = b;
}

// ---- per-token inverse L2 norm over channel axis ----
__global__ void k_xnorm(const float* __restrict__ x, float* __restrict__ invn) {
    int bh = blockIdx.x;           // b*64 + h
    int b = bh >> 6, h = bh & 63;
    int w  = threadIdx.x & 63;
    int wq = threadIdx.x >> 6;     // 0..3 (channel chunk)
    const float* base = x + (size_t)b * CHW + (size_t)h * W + w;
    float ss = 0.0f;
    for (int ch = wq * 128; ch < wq * 128 + 128; ++ch) {
        float v = base[(size_t)ch * HW];
        ss += v * v;
    }
    __shared__ float red[4][64];
    red[wq][w] = ss;
    __syncthreads();
    if (wq == 0) {
        ss = red[0][w] + red[1][w] + red[2][w] + red[3][w];
        invn[bh * 64 + w] = 1.0f / fmaxf(sqrtf(ss), 1e-12f);
    }
}

// ---- GEMM1: score[n][j] = (xf[n] . mn[j]) * invn[n], stored bf16 ----
// 64x64 tile, 256 threads (16x16), 4x4 per thread, BK=32
__global__ void __launch_bounds__(256) k_score(
        const float* __restrict__ x, const float* __restrict__ mn,
        const float* __restrict__ invn, unsigned short* __restrict__ score) {
    __shared__ float As[32][64];   // [kk][token]
    __shared__ float Bs[32][68];   // [kk][cluster], padded for 16B-aligned rows
    int tx = threadIdx.x & 15;     // token group
    int ty = threadIdx.x >> 4;     // cluster group
    int n0 = blockIdx.x * 64;
    int j0 = blockIdx.y * 64;
    int b = n0 >> 12, h = (n0 >> 6) & 63;
    const float* xbase = x + (size_t)b * CHW + (size_t)h * W;  // + ch*HW + w

    float acc[4][4] = {};
    for (int k0 = 0; k0 < C; k0 += 32) {
        {   // stage A: 32 ch x 64 tokens
            int w = threadIdx.x & 63, cq = threadIdx.x >> 6;
#pragma unroll
            for (int r = 0; r < 8; ++r) {
                int ch = r * 4 + cq;
                As[ch][w] = xbase[(size_t)(k0 + ch) * HW + w];
            }
            // stage B: 64 clusters x 32 ch
            int j = threadIdx.x >> 2;
            int kk0 = (threadIdx.x & 3) * 8;
            const float* mrow = mn + (size_t)(j0 + j) * C + k0 + kk0;
            float4 b0 = *(const float4*)mrow;
            float4 b1 = *(const float4*)(mrow + 4);
            Bs[kk0 + 0][j] = b0.x; Bs[kk0 + 1][j] = b0.y;
            Bs[kk0 + 2][j] = b0.z; Bs[kk0 + 3][j] = b0.w;
            Bs[kk0 + 4][j] = b1.x; Bs[kk0 + 5][j] = b1.y;
            Bs[kk0 + 6][j] = b1.z; Bs[kk0 + 7][j] = b1.w;
        }
        __syncthreads();
#pragma unroll
        for (int kk = 0; kk < 32; ++kk) {
            float4 av = *(const float4*)&As[kk][tx * 4];
            float4 bv = *(const float4*)&Bs[kk][ty * 4];
            float a[4] = {av.x, av.y, av.z, av.w};
            float bb[4] = {bv.x, bv.y, bv.z, bv.w};
#pragma unroll
            for (int i = 0; i < 4; ++i)
#pragma unroll
                for (int jj = 0; jj < 4; ++jj)
                    acc[i][jj] += a[i] * bb[jj];
        }
        __syncthreads();
    }
#pragma unroll
    for (int i = 0; i < 4; ++i) {
        int n = n0 + tx * 4 + i;
        float inv = invn[n];
        ushort4 pk;
        pk.x = f2bf(acc[i][0] * inv);
        pk.y = f2bf(acc[i][1] * inv);
        pk.z = f2bf(acc[i][2] * inv);
        pk.w = f2bf(acc[i][3] * inv);
        *(ushort4*)&score[(size_t)n * K + j0 + ty * 4] = pk;
    }
}

// ---- per-token row stats: argmax (first-occurrence), max, 1/sumexp; counts ----
__global__ void k_rowstats(const unsigned short* __restrict__ score,
                           float* __restrict__ smax, float* __restrict__ sinv,
                           int* __restrict__ idx, float* __restrict__ counts) {
    int wq = threadIdx.x >> 6, lane = threadIdx.x & 63;
    int n = blockIdx.x * 4 + wq;
    const unsigned short* row = score + (size_t)n * K;
    const uint4* rp = (const uint4*)(row + lane * 16);
    uint4 q0 = rp[0], q1 = rp[1];
    float vals[16];
    unsigned int ws_[8] = {q0.x, q0.y, q0.z, q0.w, q1.x, q1.y, q1.z, q1.w};
#pragma unroll
    for (int e = 0; e < 8; ++e) {
        vals[2 * e]     = bf2f(ws_[e] & 0xffffu);
        vals[2 * e + 1] = bf2f(ws_[e] >> 16);
    }
    float best = -INFINITY; int bj = 0;
#pragma unroll
    for (int e = 0; e < 16; ++e) {
        if (vals[e] > best) { best = vals[e]; bj = lane * 16 + e; }
    }
#pragma unroll
    for (int o = 32; o >= 1; o >>= 1) {
        float ov = __shfl_xor(best, o);
        int   oj = __shfl_xor(bj, o);
        if (ov > best || (ov == best && oj < bj)) { best = ov; bj = oj; }
    }
    float s = 0.0f;
#pragma unroll
    for (int e = 0; e < 16; ++e) s += __expf(vals[e] - best);
#pragma unroll
    for (int o = 32; o >= 1; o >>= 1) s += __shfl_xor(s, o);
    if (lane == 0) {
        smax[n] = best;
        sinv[n] = 1.0f / s;
        idx[n] = bj;
        atomicAdd(&counts[bj], 1.0f);
    }
}

// ---- scatter-add raw xf rows into esum[idx[n]] ----
__global__ void k_esum(const float* __restrict__ x, const int* __restrict__ idx,
                       float* __restrict__ esum) {
    int bh = blockIdx.x;
    int b = bh >> 6, h = bh & 63;
    int w  = threadIdx.x & 63;
    int wq = threadIdx.x >> 6;
    int n = bh * 64 + w;
    int cl = idx[n];
    const float* base = x + (size_t)b * CHW + (size_t)h * W + w;
    float* erow = esum + (size_t)cl * C;
    for (int ch = wq * 128; ch < wq * 128 + 128; ++ch) {
        atomicAdd(&erow[ch], base[(size_t)ch * HW]);
    }
}

// ---- new_m = 0.999*m + 0.001*esum/(counts+1e-6) ----
__global__ void k_newm(const float* __restrict__ m, const float* __restrict__ esum,
                       const float* __restrict__ counts, float* __restrict__ newm) {
    int j = blockIdx.x;
    float sc = 0.001f / (counts[j] + 1e-6f);
    for (int c = threadIdx.x; c < C; c += 256) {
        newm[(size_t)j * C + c] = 0.999f * m[(size_t)j * C + c]
                                + esum[(size_t)j * C + c] * sc;
    }
}

// ---- GEMM2: out[n][c] = sum_j exp(score-max)*inv_den * new_m[j][c], NCHW store ----
__global__ void __launch_bounds__(256) k_out(
        const unsigned short* __restrict__ score, const float* __restrict__ smax,
        const float* __restrict__ sinv, const float* __restrict__ newm,
        float* __restrict__ out) {
    __shared__ float As[32][68];   // [jj][token] = P values, padded
    __shared__ float Bs[32][64];   // [jj][c]
    int tx = threadIdx.x & 15;     // token group
    int ty = threadIdx.x >> 4;     // out-channel group
    int n0 = blockIdx.x * 64;
    int c0 = blockIdx.y * 64;
    int b = n0 >> 12, h = (n0 >> 6) & 63;

    int tok = threadIdx.x >> 2;            // for A staging
    int jj0 = (threadIdx.x & 3) * 8;
    int n_stage = n0 + tok;
    float mx = smax[n_stage];
    float inv = sinv[n_stage];
    const unsigned short* srow = score + (size_t)n_stage * K + jj0;

    int cl_c = threadIdx.x & 63;           // for B staging
    int jq = threadIdx.x >> 6;             // 0..3

    float acc[4][4] = {};
    for (int j0 = 0; j0 < K; j0 += 32) {
        {   // stage P: 64 tokens x 32 clusters (transposed into As)
            uint4 q = *(const uint4*)(srow + j0);
            unsigned int wsv[4] = {q.x, q.y, q.z, q.w};
#pragma unroll
            for (int e = 0; e < 4; ++e) {
                float v0 = bf2f(wsv[e] & 0xffffu);
                float v1 = bf2f(wsv[e] >> 16);
                As[jj0 + 2 * e][tok]     = __expf(v0 - mx) * inv;
                As[jj0 + 2 * e + 1][tok] = __expf(v1 - mx) * inv;
            }
            // stage B: 32 clusters x 64 channels, conflict-free writes
#pragma unroll
            for (int r = 0; r < 8; ++r) {
                int jj = jq * 8 + r;
                Bs[jj][cl_c] = newm[(size_t)(j0 + jj) * C + c0 + cl_c];
            }
        }
        __syncthreads();
#pragma unroll
        for (int kk = 0; kk < 32; ++kk) {
            float4 av = *(const float4*)&As[kk][tx * 4];
            float4 bv = *(const float4*)&Bs[kk][ty * 4];
            float a[4] = {av.x, av.y, av.z, av.w};
            float bb[4] = {bv.x, bv.y, bv.z, bv.w};
#pragma unroll
            for (int i = 0; i < 4; ++i)
#pragma unroll
                for (int jj = 0; jj < 4; ++jj)
                    acc[i][jj] += a[i] * bb[jj];
        }
        __syncthreads();
    }
    // store NCHW: out[b][c][h][w], tokens are consecutive w
    float* obase = out + (size_t)b * CHW + (size_t)h * W;
#pragma unroll
    for (int jj = 0; jj < 4; ++jj) {
        int ch = c0 + ty * 4 + jj;
        float4 v = make_float4(acc[0][jj], acc[1][jj], acc[2][jj], acc[3][jj]);
        *(float4*)&obase[(size_t)ch * HW + tx * 4] = v;
    }
}

extern "C" void kernel_launch(void* const* d_in, const int* in_sizes, int n_in,
                              void* d_out, int out_size, void* d_ws, size_t ws_size,
                              hipStream_t stream) {
    const float* x = (const float*)d_in[0];
    const float* m = (const float*)d_in[1];
    float* out = (float*)d_out;
    float* ws = (float*)d_ws;

    float* mn    = ws + MN_OFF;
    float* invn  = ws + INV_OFF;
    float* smax  = ws + SMAX_OFF;
    float* sinv  = ws + SDEN_OFF;
    int*   idx   = (int*)(ws + IDX_OFF);
    float* cnt   = ws + CNT_OFF;
    float* esum  = ws + ESUM_OFF;
    float* newm  = ws + NEWM_OFF;
    unsigned short* score = (unsigned short*)(ws + SCORE_OFF);

    // zero counts + esum (ws is poisoned each call)
    hipMemsetAsync(cnt, 0, (size_t)(K + K * C) * sizeof(float), stream);

    k_norm_m<<<K, 64, 0, stream>>>(m, mn);
    k_xnorm<<<B * H, 256, 0, stream>>>(x, invn);
    k_score<<<dim3(N / 64, K / 64), 256, 0, stream>>>(x, mn, invn, score);
    k_rowstats<<<N / 4, 256, 0, stream>>>(score, smax, sinv, idx, cnt);
    k_esum<<<B * H, 256, 0, stream>>>(x, idx, esum);
    k_newm<<<K, 256, 0, stream>>>(m, esum, cnt, newm);
    k_out<<<dim3(N / 64, C / 64), 256, 0, stream>>>(score, smax, sinv, newm, out);
}

// Round 3
// 766.252 us; speedup vs baseline: 2.4322x; 2.4322x over previous
//
#include <hip/hip_runtime.h>
#include <hip/hip_bf16.h>
#include <math.h>

// Problem constants
#define B 8
#define C 512
#define H 64
#define W 64
#define N 32768     // B*H*W tokens
#define K 1024      // clusters
#define HW 4096     // H*W
#define CHW 2097152 // C*H*W

typedef unsigned short u16;
typedef __attribute__((ext_vector_type(4))) float f32x4;
typedef __attribute__((ext_vector_type(8))) short bf16x8;

// ws layout (float offsets)
#define MNB_OFF   0                      // K*C/2 floats: bf16 normalized codebook
#define SMAX_OFF  (MNB_OFF + K*C/2)      // N floats: row max of score
#define SDEN_OFF  (SMAX_OFF + N)         // N floats: 1/sum(exp(s-max))
#define IDX_OFF   (SDEN_OFF + N)         // N ints: argmax
#define CNT_OFF   (IDX_OFF + N)          // K floats: counts
#define ESUM_OFF  (CNT_OFF + K)          // K*C floats
#define NEWM_OFF  (ESUM_OFF + K*C)       // K*C floats
#define SCORE_OFF (NEWM_OFF + K*C)       // N*K bf16 (u16)

static __device__ __forceinline__ u16 f2bf(float f) {
    unsigned int u = __float_as_uint(f);
    u += 0x7fffu + ((u >> 16) & 1u);   // RNE
    return (u16)(u >> 16);
}
static __device__ __forceinline__ float bf2f(unsigned int us) {
    return __uint_as_float(us << 16);
}
static __device__ __forceinline__ unsigned int pack2(float lo, float hi) {
    return (unsigned int)f2bf(lo) | ((unsigned int)f2bf(hi) << 16);
}

static __device__ __forceinline__ void gload_lds16(const void* g, void* l) {
    __builtin_amdgcn_global_load_lds(
        (const __attribute__((address_space(1))) unsigned int*)g,
        (__attribute__((address_space(3))) unsigned int*)l, 16, 0, 0);
}

// ---- normalize codebook rows -> bf16: mnb[j][c] ----
__global__ void k_norm_mb(const float* __restrict__ m, u16* __restrict__ mnb) {
    int j = blockIdx.x;
    int lane = threadIdx.x;  // 64
    const float4* mr = (const float4*)(m + (size_t)j * C);
    float4 a = mr[lane * 2], b = mr[lane * 2 + 1];
    float ss = a.x*a.x + a.y*a.y + a.z*a.z + a.w*a.w
             + b.x*b.x + b.y*b.y + b.z*b.z + b.w*b.w;
#pragma unroll
    for (int o = 32; o >= 1; o >>= 1) ss += __shfl_xor(ss, o);
    float inv = 1.0f / fmaxf(sqrtf(ss), 1e-12f);
    uint4 pk;
    pk.x = pack2(a.x * inv, a.y * inv);
    pk.y = pack2(a.z * inv, a.w * inv);
    pk.z = pack2(b.x * inv, b.y * inv);
    pk.w = pack2(b.z * inv, b.w * inv);
    *(uint4*)(mnb + (size_t)j * C + lane * 8) = pk;
}

// ---- normalize tokens + transpose to token-major bf16: xb[n][c] ----
__global__ void __launch_bounds__(256) k_prep_x(const float* __restrict__ x,
                                                u16* __restrict__ xb) {
    int bh = blockIdx.x;           // b*64 + h
    int b = bh >> 6, h = bh & 63;
    int w  = threadIdx.x & 63;
    int wq = threadIdx.x >> 6;     // 0..3 (channel quarter)
    const float* base = x + (size_t)b * CHW + (size_t)h * W + w;
    float ss = 0.0f;
    for (int ch = wq * 128; ch < wq * 128 + 128; ++ch) {
        float v = base[(size_t)ch * HW];
        ss += v * v;
    }
    __shared__ float red[4][64];
    red[wq][w] = ss;
    __syncthreads();
    float tot = red[0][w] + red[1][w] + red[2][w] + red[3][w];
    float inv = 1.0f / fmaxf(sqrtf(tot), 1e-12f);
    // pass 2: re-read this quarter (L2-hot) and emit normalized bf16 row chunk
    size_t n = (size_t)bh * 64 + w;
    u16* orow = xb + n * C;
    for (int c8 = wq * 128; c8 < wq * 128 + 128; c8 += 8) {
        float v0 = base[(size_t)(c8+0)*HW] * inv;
        float v1 = base[(size_t)(c8+1)*HW] * inv;
        float v2 = base[(size_t)(c8+2)*HW] * inv;
        float v3 = base[(size_t)(c8+3)*HW] * inv;
        float v4 = base[(size_t)(c8+4)*HW] * inv;
        float v5 = base[(size_t)(c8+5)*HW] * inv;
        float v6 = base[(size_t)(c8+6)*HW] * inv;
        float v7 = base[(size_t)(c8+7)*HW] * inv;
        uint4 pk;
        pk.x = pack2(v0, v1); pk.y = pack2(v2, v3);
        pk.z = pack2(v4, v5); pk.w = pack2(v6, v7);
        *(uint4*)&orow[c8] = pk;
    }
}

// ---- GEMM1 (MFMA): score[n][j] = xb[n] . mnb[j], bf16 out ----
// 128x128 tile, BK=64, 4 waves (2x2), 16x16x32 bf16 MFMA, m97 2-barrier structure
__global__ void __launch_bounds__(256) k_score_mfma(
        const u16* __restrict__ xb, const u16* __restrict__ mnb,
        u16* __restrict__ score) {
    __shared__ u16 As[128 * 64];   // [row][k] linear, 128B rows
    __shared__ u16 Bs[128 * 64];
    int tid = threadIdx.x;
    int lane = tid & 63;
    int wid = tid >> 6;            // 0..3
    int wm = wid >> 1, wn = wid & 1;
    int n0 = blockIdx.x * 128;
    int j0 = blockIdx.y * 128;

    f32x4 acc[4][4] = {};

    // per-lane global sources; wave wid stages rows [wid*32, wid*32+32)
    const u16* a_src = xb + (size_t)(n0 + wid*32 + (lane>>3)) * C + (lane&7)*8;
    const u16* b_src = mnb + (size_t)(j0 + wid*32 + (lane>>3)) * C + (lane&7)*8;

    for (int k0 = 0; k0 < C; k0 += 64) {
#pragma unroll
        for (int is = 0; is < 4; ++is) {
            gload_lds16(a_src + (size_t)is*8*C + k0, As + (wid*32 + is*8)*64);
            gload_lds16(b_src + (size_t)is*8*C + k0, Bs + (wid*32 + is*8)*64);
        }
        __syncthreads();   // drains vmcnt -> LDS tiles ready
#pragma unroll
        for (int kh = 0; kh < 2; ++kh) {
            int kk = kh * 32;
            bf16x8 av[4], bv[4];
#pragma unroll
            for (int f = 0; f < 4; ++f) {
                av[f] = *(const bf16x8*)&As[(wm*64 + f*16 + (lane&15))*64 + kk + (lane>>4)*8];
                bv[f] = *(const bf16x8*)&Bs[(wn*64 + f*16 + (lane&15))*64 + kk + (lane>>4)*8];
            }
#pragma unroll
            for (int fm = 0; fm < 4; ++fm)
#pragma unroll
                for (int fn = 0; fn < 4; ++fn)
                    acc[fm][fn] = __builtin_amdgcn_mfma_f32_16x16x32_bf16(
                        av[fm], bv[fn], acc[fm][fn], 0, 0, 0);
        }
        __syncthreads();   // compute done before next-tile overwrite
    }
    // epilogue: C/D layout col=lane&15, row=(lane>>4)*4+r  [m89]
    int crow = (lane >> 4) * 4;
    int ccol = lane & 15;
#pragma unroll
    for (int fm = 0; fm < 4; ++fm) {
#pragma unroll
        for (int fn = 0; fn < 4; ++fn) {
            size_t rbase = (size_t)(n0 + wm*64 + fm*16 + crow) * K
                         + (j0 + wn*64 + fn*16 + ccol);
#pragma unroll
            for (int r = 0; r < 4; ++r)
                score[rbase + (size_t)r * K] = f2bf(acc[fm][fn][r]);
        }
    }
}

// ---- per-token row stats: argmax (first occurrence), max, 1/sumexp; counts ----
__global__ void k_rowstats(const u16* __restrict__ score,
                           float* __restrict__ smax, float* __restrict__ sinv,
                           int* __restrict__ idx, float* __restrict__ counts) {
    int wq = threadIdx.x >> 6, lane = threadIdx.x & 63;
    int n = blockIdx.x * 4 + wq;
    const u16* row = score + (size_t)n * K;
    const uint4* rp = (const uint4*)(row + lane * 16);
    uint4 q0 = rp[0], q1 = rp[1];
    float vals[16];
    unsigned int ws_[8] = {q0.x, q0.y, q0.z, q0.w, q1.x, q1.y, q1.z, q1.w};
#pragma unroll
    for (int e = 0; e < 8; ++e) {
        vals[2 * e]     = bf2f(ws_[e] & 0xffffu);
        vals[2 * e + 1] = bf2f(ws_[e] >> 16);
    }
    float best = -INFINITY; int bj = 0;
#pragma unroll
    for (int e = 0; e < 16; ++e) {
        if (vals[e] > best) { best = vals[e]; bj = lane * 16 + e; }
    }
#pragma unroll
    for (int o = 32; o >= 1; o >>= 1) {
        float ov = __shfl_xor(best, o);
        int   oj = __shfl_xor(bj, o);
        if (ov > best || (ov == best && oj < bj)) { best = ov; bj = oj; }
    }
    float s = 0.0f;
#pragma unroll
    for (int e = 0; e < 16; ++e) s += __expf(vals[e] - best);
#pragma unroll
    for (int o = 32; o >= 1; o >>= 1) s += __shfl_xor(s, o);
    if (lane == 0) {
        smax[n] = best;
        sinv[n] = 1.0f / s;
        idx[n] = bj;
        atomicAdd(&counts[bj], 1.0f);
    }
}

// ---- esum via per-channel LDS-privatized scatter (no global atomics) ----
__global__ void __launch_bounds__(256) k_esum_ch(const float* __restrict__ x,
        const int* __restrict__ idx, float* __restrict__ esum) {
    int ch = blockIdx.x;           // 0..511
    __shared__ float part[K];
    for (int k = threadIdx.x; k < K; k += 256) part[k] = 0.0f;
    __syncthreads();
    const float* xc = x + (size_t)ch * HW;   // + b*CHW + hw
    for (int t = threadIdx.x; t < N / 4; t += 256) {
        int n4 = t * 4;                       // 4 consecutive tokens, same b
        int b = n4 >> 12, hw = n4 & 4095;
        float4 v = *(const float4*)(xc + (size_t)b * CHW + hw);
        int4 id = *(const int4*)(idx + n4);
        atomicAdd(&part[id.x], v.x);
        atomicAdd(&part[id.y], v.y);
        atomicAdd(&part[id.z], v.z);
        atomicAdd(&part[id.w], v.w);
    }
    __syncthreads();
    for (int k = threadIdx.x; k < K; k += 256)
        esum[(size_t)k * C + ch] = part[k];
}

// ---- new_m = 0.999*m + 0.001*esum/(counts+1e-6) ----
__global__ void k_newm(const float* __restrict__ m, const float* __restrict__ esum,
                       const float* __restrict__ counts, float* __restrict__ newm) {
    int j = blockIdx.x;
    float sc = 0.001f / (counts[j] + 1e-6f);
    for (int c = threadIdx.x; c < C; c += 256) {
        newm[(size_t)j * C + c] = 0.999f * m[(size_t)j * C + c]
                                + esum[(size_t)j * C + c] * sc;
    }
}

// ---- GEMM2 (fp32 vector): out[n][c] = softmax(score[n]) . new_m[:,c], NCHW ----
__global__ void __launch_bounds__(256) k_out(
        const u16* __restrict__ score, const float* __restrict__ smax,
        const float* __restrict__ sinv, const float* __restrict__ newm,
        float* __restrict__ out) {
    __shared__ float As[32][68];   // [jj][token] = P values, padded
    __shared__ float Bs[32][64];   // [jj][c]
    int tx = threadIdx.x & 15;     // token group
    int ty = threadIdx.x >> 4;     // out-channel group
    int n0 = blockIdx.x * 64;
    int c0 = blockIdx.y * 64;
    int b = n0 >> 12, h = (n0 >> 6) & 63;

    int tok = threadIdx.x >> 2;            // for A staging
    int jj0 = (threadIdx.x & 3) * 8;
    int n_stage = n0 + tok;
    float mx = smax[n_stage];
    float inv = sinv[n_stage];
    const u16* srow = score + (size_t)n_stage * K + jj0;

    int cl_c = threadIdx.x & 63;           // for B staging
    int jq = threadIdx.x >> 6;             // 0..3

    float acc[4][4] = {};
    for (int j0 = 0; j0 < K; j0 += 32) {
        {   // stage P: 64 tokens x 32 clusters (transposed into As)
            uint4 q = *(const uint4*)(srow + j0);
            unsigned int wsv[4] = {q.x, q.y, q.z, q.w};
#pragma unroll
            for (int e = 0; e < 4; ++e) {
                float v0 = bf2f(wsv[e] & 0xffffu);
                float v1 = bf2f(wsv[e] >> 16);
                As[jj0 + 2 * e][tok]     = __expf(v0 - mx) * inv;
                As[jj0 + 2 * e + 1][tok] = __expf(v1 - mx) * inv;
            }
#pragma unroll
            for (int r = 0; r < 8; ++r) {
                int jj = jq * 8 + r;
                Bs[jj][cl_c] = newm[(size_t)(j0 + jj) * C + c0 + cl_c];
            }
        }
        __syncthreads();
#pragma unroll
        for (int kk = 0; kk < 32; ++kk) {
            float4 av = *(const float4*)&As[kk][tx * 4];
            float4 bv = *(const float4*)&Bs[kk][ty * 4];
            float a[4] = {av.x, av.y, av.z, av.w};
            float bb[4] = {bv.x, bv.y, bv.z, bv.w};
#pragma unroll
            for (int i = 0; i < 4; ++i)
#pragma unroll
                for (int jj = 0; jj < 4; ++jj)
                    acc[i][jj] += a[i] * bb[jj];
        }
        __syncthreads();
    }
    float* obase = out + (size_t)b * CHW + (size_t)h * W;
#pragma unroll
    for (int jj = 0; jj < 4; ++jj) {
        int ch = c0 + ty * 4 + jj;
        float4 v = make_float4(acc[0][jj], acc[1][jj], acc[2][jj], acc[3][jj]);
        *(float4*)&obase[(size_t)ch * HW + tx * 4] = v;
    }
}

extern "C" void kernel_launch(void* const* d_in, const int* in_sizes, int n_in,
                              void* d_out, int out_size, void* d_ws, size_t ws_size,
                              hipStream_t stream) {
    const float* x = (const float*)d_in[0];
    const float* m = (const float*)d_in[1];
    float* out = (float*)d_out;
    float* ws = (float*)d_ws;

    u16*   mnb   = (u16*)(ws + MNB_OFF);
    float* smax  = ws + SMAX_OFF;
    float* sinv  = ws + SDEN_OFF;
    int*   idx   = (int*)(ws + IDX_OFF);
    float* cnt   = ws + CNT_OFF;
    float* esum  = ws + ESUM_OFF;
    float* newm  = ws + NEWM_OFF;
    u16*   score = (u16*)(ws + SCORE_OFF);
    // xb (normalized tokens, bf16 [N][C], 32MB) lives in d_out scratch:
    // dead before k_out runs, and k_out fully overwrites d_out.
    u16*   xb    = (u16*)d_out;

    hipMemsetAsync(cnt, 0, (size_t)K * sizeof(float), stream);

    k_norm_mb<<<K, 64, 0, stream>>>(m, mnb);
    k_prep_x<<<B * H, 256, 0, stream>>>(x, xb);
    k_score_mfma<<<dim3(N / 128, K / 128), 256, 0, stream>>>(xb, mnb, score);
    k_rowstats<<<N / 4, 256, 0, stream>>>(score, smax, sinv, idx, cnt);
    k_esum_ch<<<C, 256, 0, stream>>>(x, idx, esum);
    k_newm<<<K, 256, 0, stream>>>(m, esum, cnt, newm);
    k_out<<<dim3(N / 64, C / 64), 256, 0, stream>>>(score, smax, sinv, newm, out);
}

// Round 4
// 377.266 us; speedup vs baseline: 4.9399x; 2.0311x over previous
//
#include <hip/hip_runtime.h>
#include <hip/hip_bf16.h>
#include <math.h>

// Problem constants
#define B 8
#define C 512
#define H 64
#define W 64
#define N 32768     // B*H*W tokens
#define K 1024      // clusters
#define HW 4096     // H*W
#define CHW 2097152 // C*H*W

typedef unsigned short u16;
typedef __attribute__((ext_vector_type(4))) float f32x4;
typedef __attribute__((ext_vector_type(8))) short bf16x8;

// ws layout (float offsets)
#define MNB_OFF   0                      // K*C u16: bf16 normalized codebook [j][c]
#define IDX_OFF   (MNB_OFF + K*C/2)      // N ints: argmax
#define CNT_OFF   (IDX_OFF + N)          // K floats: counts
#define ESUM_OFF  (CNT_OFF + K)          // K*C floats
#define NMT_OFF   (ESUM_OFF + K*C)       // C*K u16: bf16 new_m transposed [c][j]
#define SCORE_OFF (NMT_OFF + K*C/2)      // N*K u16: bf16 score, then P in-place

static __device__ __forceinline__ u16 f2bf(float f) {
    unsigned int u = __float_as_uint(f);
    u += 0x7fffu + ((u >> 16) & 1u);   // RNE
    return (u16)(u >> 16);
}
static __device__ __forceinline__ float bf2f(unsigned int us) {
    return __uint_as_float(us << 16);
}
static __device__ __forceinline__ unsigned int pack2(float lo, float hi) {
    return (unsigned int)f2bf(lo) | ((unsigned int)f2bf(hi) << 16);
}

static __device__ __forceinline__ void gload_lds16(const void* g, void* l) {
    __builtin_amdgcn_global_load_lds(
        (const __attribute__((address_space(1))) unsigned int*)g,
        (__attribute__((address_space(3))) unsigned int*)l, 16, 0, 0);
}

// ---- normalize codebook rows -> bf16: mnb[j][c] ----
__global__ void k_norm_mb(const float* __restrict__ m, u16* __restrict__ mnb) {
    int j = blockIdx.x;
    int lane = threadIdx.x;  // 64
    const float4* mr = (const float4*)(m + (size_t)j * C);
    float4 a = mr[lane * 2], b = mr[lane * 2 + 1];
    float ss = a.x*a.x + a.y*a.y + a.z*a.z + a.w*a.w
             + b.x*b.x + b.y*b.y + b.z*b.z + b.w*b.w;
#pragma unroll
    for (int o = 32; o >= 1; o >>= 1) ss += __shfl_xor(ss, o);
    float inv = 1.0f / fmaxf(sqrtf(ss), 1e-12f);
    uint4 pk;
    pk.x = pack2(a.x * inv, a.y * inv);
    pk.y = pack2(a.z * inv, a.w * inv);
    pk.z = pack2(b.x * inv, b.y * inv);
    pk.w = pack2(b.z * inv, b.w * inv);
    *(uint4*)(mnb + (size_t)j * C + lane * 8) = pk;
}

// ---- normalize tokens + transpose to token-major bf16: xb[n][c] ----
__global__ void __launch_bounds__(256) k_prep_x(const float* __restrict__ x,
                                                u16* __restrict__ xb) {
    int bh = blockIdx.x;           // b*64 + h
    int b = bh >> 6, h = bh & 63;
    int w  = threadIdx.x & 63;
    int wq = threadIdx.x >> 6;     // 0..3 (channel quarter)
    const float* base = x + (size_t)b * CHW + (size_t)h * W + w;
    float ss = 0.0f;
    for (int ch = wq * 128; ch < wq * 128 + 128; ++ch) {
        float v = base[(size_t)ch * HW];
        ss += v * v;
    }
    __shared__ float red[4][64];
    red[wq][w] = ss;
    __syncthreads();
    float tot = red[0][w] + red[1][w] + red[2][w] + red[3][w];
    float inv = 1.0f / fmaxf(sqrtf(tot), 1e-12f);
    size_t n = (size_t)bh * 64 + w;
    u16* orow = xb + n * C;
    for (int c8 = wq * 128; c8 < wq * 128 + 128; c8 += 8) {
        float v0 = base[(size_t)(c8+0)*HW] * inv;
        float v1 = base[(size_t)(c8+1)*HW] * inv;
        float v2 = base[(size_t)(c8+2)*HW] * inv;
        float v3 = base[(size_t)(c8+3)*HW] * inv;
        float v4 = base[(size_t)(c8+4)*HW] * inv;
        float v5 = base[(size_t)(c8+5)*HW] * inv;
        float v6 = base[(size_t)(c8+6)*HW] * inv;
        float v7 = base[(size_t)(c8+7)*HW] * inv;
        uint4 pk;
        pk.x = pack2(v0, v1); pk.y = pack2(v2, v3);
        pk.z = pack2(v4, v5); pk.w = pack2(v6, v7);
        *(uint4*)&orow[c8] = pk;
    }
}

// ---- GEMM1 (MFMA): score[n][j] = xb[n] . mnb[j], bf16 out ----
// 128x128 tile, BK=64, 4 waves (2x2), 16x16x32 bf16 MFMA, m97 2-barrier structure
__global__ void __launch_bounds__(256) k_score_mfma(
        const u16* __restrict__ xb, const u16* __restrict__ mnb,
        u16* __restrict__ score) {
    __shared__ u16 As[128 * 64];   // [row][k] linear, 128B rows
    __shared__ u16 Bs[128 * 64];
    int tid = threadIdx.x;
    int lane = tid & 63;
    int wid = tid >> 6;            // 0..3
    int wm = wid >> 1, wn = wid & 1;
    int n0 = blockIdx.x * 128;
    int j0 = blockIdx.y * 128;

    f32x4 acc[4][4] = {};

    const u16* a_src = xb + (size_t)(n0 + wid*32 + (lane>>3)) * C + (lane&7)*8;
    const u16* b_src = mnb + (size_t)(j0 + wid*32 + (lane>>3)) * C + (lane&7)*8;

    for (int k0 = 0; k0 < C; k0 += 64) {
#pragma unroll
        for (int is = 0; is < 4; ++is) {
            gload_lds16(a_src + (size_t)is*8*C + k0, As + (wid*32 + is*8)*64);
            gload_lds16(b_src + (size_t)is*8*C + k0, Bs + (wid*32 + is*8)*64);
        }
        __syncthreads();
#pragma unroll
        for (int kh = 0; kh < 2; ++kh) {
            int kk = kh * 32;
            bf16x8 av[4], bv[4];
#pragma unroll
            for (int f = 0; f < 4; ++f) {
                av[f] = *(const bf16x8*)&As[(wm*64 + f*16 + (lane&15))*64 + kk + (lane>>4)*8];
                bv[f] = *(const bf16x8*)&Bs[(wn*64 + f*16 + (lane&15))*64 + kk + (lane>>4)*8];
            }
#pragma unroll
            for (int fm = 0; fm < 4; ++fm)
#pragma unroll
                for (int fn = 0; fn < 4; ++fn)
                    acc[fm][fn] = __builtin_amdgcn_mfma_f32_16x16x32_bf16(
                        av[fm], bv[fn], acc[fm][fn], 0, 0, 0);
        }
        __syncthreads();
    }
    int crow = (lane >> 4) * 4;
    int ccol = lane & 15;
#pragma unroll
    for (int fm = 0; fm < 4; ++fm) {
#pragma unroll
        for (int fn = 0; fn < 4; ++fn) {
            size_t rbase = (size_t)(n0 + wm*64 + fm*16 + crow) * K
                         + (j0 + wn*64 + fn*16 + ccol);
#pragma unroll
            for (int r = 0; r < 4; ++r)
                score[rbase + (size_t)r * K] = f2bf(acc[fm][fn][r]);
        }
    }
}

// ---- row stats + in-place softmax: score -> P = exp(s-max)/sumexp (bf16) ----
__global__ void k_rowstats(u16* __restrict__ score,
                           int* __restrict__ idx, float* __restrict__ counts) {
    int wq = threadIdx.x >> 6, lane = threadIdx.x & 63;
    int n = blockIdx.x * 4 + wq;
    u16* row = score + (size_t)n * K;
    uint4* rp = (uint4*)(row + lane * 16);
    uint4 q0 = rp[0], q1 = rp[1];
    float vals[16];
    unsigned int ws_[8] = {q0.x, q0.y, q0.z, q0.w, q1.x, q1.y, q1.z, q1.w};
#pragma unroll
    for (int e = 0; e < 8; ++e) {
        vals[2 * e]     = bf2f(ws_[e] & 0xffffu);
        vals[2 * e + 1] = bf2f(ws_[e] >> 16);
    }
    float best = -INFINITY; int bj = 0;
#pragma unroll
    for (int e = 0; e < 16; ++e) {
        if (vals[e] > best) { best = vals[e]; bj = lane * 16 + e; }
    }
#pragma unroll
    for (int o = 32; o >= 1; o >>= 1) {
        float ov = __shfl_xor(best, o);
        int   oj = __shfl_xor(bj, o);
        if (ov > best || (ov == best && oj < bj)) { best = ov; bj = oj; }
    }
    float p[16];
    float s = 0.0f;
#pragma unroll
    for (int e = 0; e < 16; ++e) { p[e] = __expf(vals[e] - best); s += p[e]; }
#pragma unroll
    for (int o = 32; o >= 1; o >>= 1) s += __shfl_xor(s, o);
    float sinv = 1.0f / s;
    // write P back in place (each lane owns its own 16 columns)
    uint4 o0, o1;
    o0.x = pack2(p[0]*sinv,  p[1]*sinv);
    o0.y = pack2(p[2]*sinv,  p[3]*sinv);
    o0.z = pack2(p[4]*sinv,  p[5]*sinv);
    o0.w = pack2(p[6]*sinv,  p[7]*sinv);
    o1.x = pack2(p[8]*sinv,  p[9]*sinv);
    o1.y = pack2(p[10]*sinv, p[11]*sinv);
    o1.z = pack2(p[12]*sinv, p[13]*sinv);
    o1.w = pack2(p[14]*sinv, p[15]*sinv);
    rp[0] = o0; rp[1] = o1;
    if (lane == 0) {
        idx[n] = bj;
        atomicAdd(&counts[bj], 1.0f);
    }
}

// ---- esum via per-channel LDS-privatized scatter (no global atomics) ----
__global__ void __launch_bounds__(256) k_esum_ch(const float* __restrict__ x,
        const int* __restrict__ idx, float* __restrict__ esum) {
    int ch = blockIdx.x;           // 0..511
    __shared__ float part[K];
    for (int k = threadIdx.x; k < K; k += 256) part[k] = 0.0f;
    __syncthreads();
    const float* xc = x + (size_t)ch * HW;   // + b*CHW + hw
    for (int t = threadIdx.x; t < N / 4; t += 256) {
        int n4 = t * 4;
        int b = n4 >> 12, hw = n4 & 4095;
        float4 v = *(const float4*)(xc + (size_t)b * CHW + hw);
        int4 id = *(const int4*)(idx + n4);
        atomicAdd(&part[id.x], v.x);
        atomicAdd(&part[id.y], v.y);
        atomicAdd(&part[id.z], v.z);
        atomicAdd(&part[id.w], v.w);
    }
    __syncthreads();
    for (int k = threadIdx.x; k < K; k += 256)
        esum[(size_t)k * C + ch] = part[k];
}

// ---- new_m transposed bf16: nmt[c][j] = 0.999*m[j][c] + 0.001*esum[j][c]/(cnt[j]+eps) ----
// 64x64 LDS tile transpose per block
__global__ void __launch_bounds__(256) k_newm_t(const float* __restrict__ m,
        const float* __restrict__ esum, const float* __restrict__ counts,
        u16* __restrict__ nmt) {
    __shared__ float tile[64][65];
    int jb = blockIdx.x * 64, cb = blockIdx.y * 64;
    int cl = threadIdx.x & 63, jq = threadIdx.x >> 6;   // jq 0..3
#pragma unroll
    for (int r = 0; r < 16; ++r) {
        int jl = jq * 16 + r;
        int j = jb + jl;
        float sc = 0.001f / (counts[j] + 1e-6f);
        size_t off = (size_t)j * C + cb + cl;
        tile[jl][cl] = 0.999f * m[off] + esum[off] * sc;
    }
    __syncthreads();
    int crow = threadIdx.x >> 2;        // 0..63 output c row
    int q = threadIdx.x & 3;            // j quarter (16 each)
    uint4 lo, hi;
    float v0  = tile[q*16+ 0][crow], v1  = tile[q*16+ 1][crow];
    float v2  = tile[q*16+ 2][crow], v3  = tile[q*16+ 3][crow];
    float v4  = tile[q*16+ 4][crow], v5  = tile[q*16+ 5][crow];
    float v6  = tile[q*16+ 6][crow], v7  = tile[q*16+ 7][crow];
    float v8  = tile[q*16+ 8][crow], v9  = tile[q*16+ 9][crow];
    float v10 = tile[q*16+10][crow], v11 = tile[q*16+11][crow];
    float v12 = tile[q*16+12][crow], v13 = tile[q*16+13][crow];
    float v14 = tile[q*16+14][crow], v15 = tile[q*16+15][crow];
    lo.x = pack2(v0, v1);  lo.y = pack2(v2, v3);
    lo.z = pack2(v4, v5);  lo.w = pack2(v6, v7);
    hi.x = pack2(v8, v9);  hi.y = pack2(v10, v11);
    hi.z = pack2(v12, v13); hi.w = pack2(v14, v15);
    u16* orow = nmt + (size_t)(cb + crow) * K + jb + q * 16;
    *(uint4*)orow = lo;
    *(uint4*)(orow + 8) = hi;
}

// ---- GEMM2 (MFMA): out[n][c] = P[n] . nmt[c], fp32 NCHW store ----
// Same 128x128/BK64 structure; K-dim = 1024 clusters
__global__ void __launch_bounds__(256) k_out_mfma(
        const u16* __restrict__ P, const u16* __restrict__ nmt,
        float* __restrict__ out) {
    __shared__ u16 As[128 * 64];
    __shared__ u16 Bs[128 * 64];
    int tid = threadIdx.x;
    int lane = tid & 63;
    int wid = tid >> 6;
    int wm = wid >> 1, wn = wid & 1;
    int n0 = blockIdx.x * 128;
    int c0 = blockIdx.y * 128;

    f32x4 acc[4][4] = {};

    const u16* a_src = P   + (size_t)(n0 + wid*32 + (lane>>3)) * K + (lane&7)*8;
    const u16* b_src = nmt + (size_t)(c0 + wid*32 + (lane>>3)) * K + (lane&7)*8;

    for (int k0 = 0; k0 < K; k0 += 64) {
#pragma unroll
        for (int is = 0; is < 4; ++is) {
            gload_lds16(a_src + (size_t)is*8*K + k0, As + (wid*32 + is*8)*64);
            gload_lds16(b_src + (size_t)is*8*K + k0, Bs + (wid*32 + is*8)*64);
        }
        __syncthreads();
#pragma unroll
        for (int kh = 0; kh < 2; ++kh) {
            int kk = kh * 32;
            bf16x8 av[4], bv[4];
#pragma unroll
            for (int f = 0; f < 4; ++f) {
                av[f] = *(const bf16x8*)&As[(wm*64 + f*16 + (lane&15))*64 + kk + (lane>>4)*8];
                bv[f] = *(const bf16x8*)&Bs[(wn*64 + f*16 + (lane&15))*64 + kk + (lane>>4)*8];
            }
#pragma unroll
            for (int fm = 0; fm < 4; ++fm)
#pragma unroll
                for (int fn = 0; fn < 4; ++fn)
                    acc[fm][fn] = __builtin_amdgcn_mfma_f32_16x16x32_bf16(
                        av[fm], bv[fn], acc[fm][fn], 0, 0, 0);
        }
        __syncthreads();
    }
    // store NCHW: n = n0 + wm*64 + fm*16 + crow + r (consecutive w for r=0..3)
    int b = n0 >> 12;
    int hw0 = (n0 & 4095) + wm * 64;
    int crow = (lane >> 4) * 4;
    int ccol = lane & 15;
    float* obase = out + (size_t)b * CHW;
#pragma unroll
    for (int fm = 0; fm < 4; ++fm) {
#pragma unroll
        for (int fn = 0; fn < 4; ++fn) {
            int ch = c0 + wn * 64 + fn * 16 + ccol;
            int hw = hw0 + fm * 16 + crow;
            float4 v = make_float4(acc[fm][fn][0], acc[fm][fn][1],
                                   acc[fm][fn][2], acc[fm][fn][3]);
            *(float4*)&obase[(size_t)ch * HW + hw] = v;
        }
    }
}

extern "C" void kernel_launch(void* const* d_in, const int* in_sizes, int n_in,
                              void* d_out, int out_size, void* d_ws, size_t ws_size,
                              hipStream_t stream) {
    const float* x = (const float*)d_in[0];
    const float* m = (const float*)d_in[1];
    float* out = (float*)d_out;
    float* ws = (float*)d_ws;

    u16*   mnb   = (u16*)(ws + MNB_OFF);
    int*   idx   = (int*)(ws + IDX_OFF);
    float* cnt   = ws + CNT_OFF;
    float* esum  = ws + ESUM_OFF;
    u16*   nmt   = (u16*)(ws + NMT_OFF);
    u16*   score = (u16*)(ws + SCORE_OFF);
    // xb (normalized tokens, bf16 [N][C], 32MB) borrows d_out: dead before
    // k_out_mfma runs, and k_out_mfma fully overwrites d_out.
    u16*   xb    = (u16*)d_out;

    hipMemsetAsync(cnt, 0, (size_t)K * sizeof(float), stream);

    k_norm_mb<<<K, 64, 0, stream>>>(m, mnb);
    k_prep_x<<<B * H, 256, 0, stream>>>(x, xb);
    k_score_mfma<<<dim3(N / 128, K / 128), 256, 0, stream>>>(xb, mnb, score);
    k_rowstats<<<N / 4, 256, 0, stream>>>(score, idx, cnt);
    k_esum_ch<<<C, 256, 0, stream>>>(x, idx, esum);
    k_newm_t<<<dim3(K / 64, C / 64), 256, 0, stream>>>(m, esum, cnt, nmt);
    k_out_mfma<<<dim3(N / 128, C / 128), 256, 0, stream>>>(score, nmt, out);
}